// Round 9
// baseline (7454.178 us; speedup 1.0000x reference)
//
#include <hip/hip_runtime.h>
#include <hip/hip_fp16.h>

// LSTM B=64, T=1024, I=256, H=512 — persistent weight-stationary,
// self-announcing data exchange with PER-DWORD generation tags.
// PLAIN (non-cooperative) launch: no grid.sync anywhere; co-residency of the
// 128 WGs is structural (128 WGs <= 256 CUs, launch_bounds(256,1) => >=1
// WG/CU at any VGPR count), and plain launches have no occupancy validation
// that can silently reject the kernel (rounds 5-8: hipLaunchCooperativeKernel
// returned an error that was ignored -> kernel never ran -> out = b_fc).
//
// 128 WGs x 256 thr; wave w of WG g owns batch rows [16w,16w+16) x h-cols
// [4g,4g+4) (16 gate cols). Weights [768,16] f16 in registers (24 B-frags).
//
// Exchange: h stored as u64 packets (4 f16). EACH DWORD embeds the full
// 4-bit generation tag (t mod 15)+1 in the 2 LSBs of its two f16s. Consumer
// accepts a packet only if BOTH dwords carry the expected tag (torn 8-B
// stores can't pass; zeros/0xAA poison decode as tag 0, unrepresentable).
// Consumers poll the data directly: the sweep IS the 32 u64 loads + tag
// check, retried with s_sleep. No producer drain, no flags on the critical
// path, no __syncthreads. Critical path = store flight + <=2 sweeps.
//
// Buffering: 3 slots, zeroed each launch; iter t reads slot t%3 (h_{t-1}),
// writes slot (t+1)%3 (h_t). Tag collision needs generation gap 15; backward
// guard (per-wave progress flags P, min P >= t-2 before store) bounds the
// gap to ~4. Guard loads issued early, checked post-epilogue; +2-margin
// caching skips most checks. P zeroed each launch.

#define T_STEPS 1024
#define BATCH   64
#define ISZ     256
#define HSZ     512
#define NWG     128
#define NTHR    256
#define HB4     ((BATCH * HSZ) / 4)   // u64 per h buffer (8192)
#define NBUF    3
#define TAGMASK 0x0003000300030003ULL

typedef _Float16 half8  __attribute__((ext_vector_type(8)));
typedef _Float16 half4  __attribute__((ext_vector_type(4)));
typedef float    floatx4 __attribute__((ext_vector_type(4)));
typedef unsigned long long u64;

#define LD_AGENT(p)     __hip_atomic_load((p), __ATOMIC_RELAXED, __HIP_MEMORY_SCOPE_AGENT)
#define ST_AGENT(p, v)  __hip_atomic_store((p), (v), __ATOMIC_RELAXED, __HIP_MEMORY_SCOPE_AGENT)

__device__ __forceinline__ float fast_sigmoid(float x) {
    return 1.0f / (1.0f + __expf(-x));
}
__device__ __forceinline__ float fast_tanh(float x) {
    return 1.0f - 2.0f / (__expf(2.0f * x) + 1.0f);
}
// v in 1..15 -> full 4-bit tag embedded in EACH dword: bits {0,1} of the low
// f16 carry v&3, bits {16,17} (low bits of the high f16) carry v>>2.
__device__ __forceinline__ u64 tagbits(int v) {
    u64 d = (u64)(v & 3) | ((u64)((v >> 2) & 3) << 16);
    return d | (d << 32);
}

__global__ __launch_bounds__(NTHR, 1) void lstm_persist(
    const float* __restrict__ x,
    const float* __restrict__ Wf, const float* __restrict__ bfv,
    const float* __restrict__ Wi, const float* __restrict__ biv,
    const float* __restrict__ Wc, const float* __restrict__ bcv,
    const float* __restrict__ Wo, const float* __restrict__ bov,
    u64* __restrict__ hbuf4, unsigned* __restrict__ pflags)
{
    const int g    = blockIdx.x;        // 0..127
    const int tid  = threadIdx.x;
    const int w    = tid >> 6;          // wave -> row-block [16w,16w+16)
    const int l    = tid & 63;
    const int lj   = l & 15;
    const int lk   = l >> 4;
    const int gate = lj >> 2;           // 0=f 1=i 2=c~ 3=o
    const int jc   = lj & 3;
    const int hc   = (g << 2) + jc;     // h column
    const int row0 = w << 4;
    const int arow = row0 + lj;         // A-operand batch row
    const int pidx = (g << 2) + w;      // per-wave progress-flag index 0..511

    const float* Wg = (gate == 0) ? Wf : (gate == 1) ? Wi : (gate == 2) ? Wc : Wo;
    const float* bg = (gate == 0) ? bfv : (gate == 1) ? biv : (gate == 2) ? bcv : bov;

    // Weight fragments, resident for all 1024 steps. k in fragment =
    // kf*32 + lk*8 + e; A-fragments use the identical k mapping.
    half8 Bfrag[24];
    #pragma unroll
    for (int kf = 0; kf < 24; ++kf) {
        half8 v;
        #pragma unroll
        for (int e = 0; e < 8; ++e) {
            int k = (kf << 5) + (lk << 3) + e;
            v[e] = (_Float16)Wg[(size_t)k * HSZ + hc];
        }
        Bfrag[kf] = v;
    }
    const float bias = bg[hc];
    float cst[4] = {0.f, 0.f, 0.f, 0.f};

    const u64* pfl = (const u64*)pflags;   // 256 u64 = 512 u32 progress flags

    // x-part for t=0 (h_{-1}=0: gates = x-part + bias)
    floatx4 accx = {0.f, 0.f, 0.f, 0.f};
    {
        const float* xr = x + (size_t)arow * T_STEPS * ISZ + (lk << 3);
        #pragma unroll
        for (int kf = 0; kf < 8; ++kf) {
            floatx4 x0 = *(const floatx4*)(xr + (kf << 5));
            floatx4 x1 = *(const floatx4*)(xr + (kf << 5) + 4);
            half8 a;
            a[0] = (_Float16)x0[0]; a[1] = (_Float16)x0[1];
            a[2] = (_Float16)x0[2]; a[3] = (_Float16)x0[3];
            a[4] = (_Float16)x1[0]; a[5] = (_Float16)x1[1];
            a[6] = (_Float16)x1[2]; a[7] = (_Float16)x1[3];
            accx = __builtin_amdgcn_mfma_f32_16x16x32_f16(a, Bfrag[kf], accx, 0, 0, 0);
        }
    }

    unsigned minP_seen = 0;   // cached lower bound on global min progress

    for (int t = 0; t < T_STEPS; ++t) {
        u64 hl[32];
        u64 pv[4] = {0, 0, 0, 0};
        const bool need_guard = (t >= 3) && (minP_seen < (unsigned)(t - 2));

        if (t > 0) {
            // ---- self-announcing sweep: loads ARE the poll ----
            const u64 expp = tagbits(((t - 1) % 15) + 1);
            const u64* hr = hbuf4 + (size_t)(t % NBUF) * HB4 + arow;
            for (;;) {
                #pragma unroll
                for (int kf = 0; kf < 16; ++kf) {
                    const int c0 = kf * 8 + lk * 2;
                    hl[2 * kf]     = LD_AGENT(hr + (size_t)c0 * BATCH);
                    hl[2 * kf + 1] = LD_AGENT(hr + (size_t)(c0 + 1) * BATCH);
                }
                bool ok = true;
                #pragma unroll
                for (int i = 0; i < 32; ++i) ok &= ((hl[i] & TAGMASK) == expp);
                if (__all(ok)) break;
                __builtin_amdgcn_s_sleep(1);
            }
            // publish progress (fire-and-forget; loads already completed)
            if (l == 0) ST_AGENT(&pflags[pidx], (unsigned)t);
            // early-issue backward-guard loads (consumed post-epilogue)
            if (need_guard) {
                #pragma unroll
                for (int j = 0; j < 4; ++j) pv[j] = LD_AGENT(pfl + l + (j << 6));
            }
        }

        floatx4 acc0, acc1;
        #pragma unroll
        for (int e = 0; e < 4; ++e) { acc0[e] = accx[e] + bias; acc1[e] = 0.f; }

        if (t > 0) {
            // two independent 8-deep MFMA chains
            #pragma unroll
            for (int kf = 0; kf < 16; kf += 2) {
                union { u64 u[2]; half8 h; } a0, a1;
                a0.u[0] = hl[2 * kf];     a0.u[1] = hl[2 * kf + 1];
                a1.u[0] = hl[2 * kf + 2]; a1.u[1] = hl[2 * kf + 3];
                acc0 = __builtin_amdgcn_mfma_f32_16x16x32_f16(a0.h, Bfrag[8 + kf], acc0, 0, 0, 0);
                acc1 = __builtin_amdgcn_mfma_f32_16x16x32_f16(a1.h, Bfrag[9 + kf], acc1, 0, 0, 0);
            }
        }

        // activations (gate uniform per lane)
        floatx4 act;
        if (gate == 2) {
            #pragma unroll
            for (int e = 0; e < 4; ++e) act[e] = fast_tanh(acc0[e] + acc1[e]);
        } else {
            #pragma unroll
            for (int e = 0; e < 4; ++e) act[e] = fast_sigmoid(acc0[e] + acc1[e]);
        }

        // broadcast 4 gate values within each (lk,jc) quartet; replicated c-state
        const int base = l & ~12;
        float hv[4];
        #pragma unroll
        for (int e = 0; e < 4; ++e) {
            float vf = __shfl(act[e], base);
            float vi = __shfl(act[e], base + 4);
            float vc = __shfl(act[e], base + 8);
            float vo = __shfl(act[e], base + 12);
            float c  = vf * cst[e] + vi * vc;
            cst[e] = c;
            hv[e] = vo * fast_tanh(c);
        }

        // shfl-transpose: lane L<16 gathers row row0+L, cols 4g..4g+4 (u64)
        half4 outv;
        #pragma unroll
        for (int col = 0; col < 4; ++col) {
            const int src = ((l & 15) >> 2) * 16 + col;
            float sel = 0.f;
            #pragma unroll
            for (int e = 0; e < 4; ++e) {
                float tmp = __shfl(hv[e], src);
                if ((l & 3) == e) sel = tmp;
            }
            outv[col] = (_Float16)sel;
        }

        // backward guard: all waves' iteration-(t-2) loads must be done before
        // we overwrite slot (t+1)%3 (which holds h_{t-3}, read in iter t-2).
        if (need_guard) {
            const unsigned need = (unsigned)(t - 2);
            for (;;) {
                unsigned m = 0xffffffffu;
                #pragma unroll
                for (int j = 0; j < 4; ++j) {
                    unsigned lo = (unsigned)pv[j], hi = (unsigned)(pv[j] >> 32);
                    m = m < lo ? m : lo;
                    m = m < hi ? m : hi;
                }
                if (__all(m >= need + 2)) { minP_seen = need + 2; break; }
                if (__all(m >= need)) break;
                __builtin_amdgcn_s_sleep(1);
                #pragma unroll
                for (int j = 0; j < 4; ++j) pv[j] = LD_AGENT(pfl + l + (j << 6));
            }
        }

        // per-dword tagged stores: fire-and-forget, no drain, no flag
        u64* hw = hbuf4 + (size_t)((t + 1) % NBUF) * HB4 + (size_t)g * BATCH + row0;
        if (l < 16) {
            union { half4 h; u64 u; } pk; pk.h = outv;
            pk.u = (pk.u & ~TAGMASK) | tagbits((t % 15) + 1);
            ST_AGENT(hw + l, pk.u);
        }

        // x-part of step t+1 from fresh loads, hidden in the store shadow
        // (round-4 style: keeps peak VGPR low; loads overlap others' sweeps)
        if (t + 1 < T_STEPS) {
            floatx4 az = {0.f, 0.f, 0.f, 0.f};
            const float* xr = x + ((size_t)arow * T_STEPS + (t + 1)) * ISZ + (lk << 3);
            #pragma unroll
            for (int kf = 0; kf < 8; ++kf) {
                floatx4 x0 = *(const floatx4*)(xr + (kf << 5));
                floatx4 x1 = *(const floatx4*)(xr + (kf << 5) + 4);
                half8 a;
                a[0] = (_Float16)x0[0]; a[1] = (_Float16)x0[1];
                a[2] = (_Float16)x0[2]; a[3] = (_Float16)x0[3];
                a[4] = (_Float16)x1[0]; a[5] = (_Float16)x1[1];
                a[6] = (_Float16)x1[2]; a[7] = (_Float16)x1[3];
                az = __builtin_amdgcn_mfma_f32_16x16x32_f16(a, Bfrag[kf], az, 0, 0, 0);
            }
            accx = az;
        }
    }
}

// final h = h_{1023}, stored during t=1023 into slot (1023+1)%3 = 1
__global__ void out_proj(const u64* __restrict__ hb4, const float* __restrict__ Wfc,
                         const float* __restrict__ bfc, float* __restrict__ out)
{
    const int b = blockIdx.x;      // 64
    const int l = threadIdx.x;     // 64
    float s = 0.f;
    #pragma unroll
    for (int j = 0; j < 2; ++j) {
        const int c4 = l + (j << 6);
        union { u64 u; half4 h; } v;
        v.u = hb4[(size_t)c4 * BATCH + b];
        #pragma unroll
        for (int q = 0; q < 4; ++q)
            s += (float)v.h[q] * Wfc[c4 * 4 + q];
    }
    #pragma unroll
    for (int off = 32; off; off >>= 1) s += __shfl_down(s, off);
    if (l == 0) out[b] = s + bfc[0];
}

extern "C" void kernel_launch(void* const* d_in, const int* in_sizes, int n_in,
                              void* d_out, int out_size, void* d_ws, size_t ws_size,
                              hipStream_t stream)
{
    const float* x   = (const float*)d_in[0];
    const float* Wf  = (const float*)d_in[1];
    const float* bf  = (const float*)d_in[2];
    const float* Wi  = (const float*)d_in[3];
    const float* bi  = (const float*)d_in[4];
    const float* Wc  = (const float*)d_in[5];
    const float* bc  = (const float*)d_in[6];
    const float* Wo  = (const float*)d_in[7];
    const float* bo  = (const float*)d_in[8];
    const float* Wfc = (const float*)d_in[9];
    const float* bfc = (const float*)d_in[10];

    u64* hbuf4 = (u64*)d_ws;                                   // 3*8192*8 = 192 KB
    unsigned* pflags = (unsigned*)((char*)d_ws + (size_t)NBUF * HB4 * sizeof(u64));

    // Zero h slots + progress flags every launch: erases 0xAA poison, stale
    // replay data, and garbage on first call. Tags are 1..15 and zeroed dwords
    // decode as tag 0, so zeroed packets can never pass a sweep.
    (void)hipMemsetAsync(hbuf4, 0,
                         (size_t)NBUF * HB4 * sizeof(u64) + 512 * sizeof(unsigned),
                         stream);

    // PLAIN launch (not cooperative): no grid.sync used; 128 WGs <= 256 CUs
    // all become resident immediately (launch_bounds guarantees >=1 WG/CU).
    lstm_persist<<<dim3(NWG), dim3(NTHR), 0, stream>>>(
        x, Wf, bf, Wi, bi, Wc, bc, Wo, bo, hbuf4, pflags);

    const u64* hfinal = hbuf4 + (size_t)(T_STEPS % NBUF) * HB4;   // slot 1
    out_proj<<<dim3(BATCH), dim3(64), 0, stream>>>(hfinal, Wfc, bfc, (float*)d_out);
}